// Round 4
// baseline (546.700 us; speedup 1.0000x reference)
//
#include <hip/hip_runtime.h>
#include <hip/hip_bf16.h>

// Problem constants (from reference)
constexpr int HH    = 1024;
constexpr int WW    = 1024;
constexpr int NPIX  = HH * WW;        // 1,048,576 pixels
constexpr int NB    = 16;             // batch replication factor
constexpr int BLOCK = 256;
constexpr int MAPF4 = NPIX * 3 / 4;   // float4s per batch image = 786432
constexpr int CHUNKS = MAPF4 / BLOCK; // 3072 blocks per batch image

// Native vector type — __builtin_nontemporal_store rejects HIP_vector_type.
typedef float vfloat4 __attribute__((ext_vector_type(4)));

// Wire dtypes (evidence prior session): verts/bary f32, faces/p2f int32,
// out f32. out(n,h,w,d) is batch-invariant (reference gathers all batches
// from batch-0 face attrs; batch-0 packing offset is 0).
//
// R4 structure: FUSED compute-on-store, ONE BATCH IMAGE PER BLOCK.
//
// History of the store pattern (each step counter-verified):
//   R2: per-thread 48 B-stride NT stores -> 1/3-density lines -> 1.82x
//       WRITE_SIZE amplification, 2.6 TB/s.  (partial-line bursts)
//   R3: dense per-instruction stores but each wave wrote 16 streams at
//       12 MiB (3*2^22) stride -> per-channel DRAM row thrash -> ~94 us,
//       still ~3x the write floor, WRITE_SIZE clean.  (row locality)
//   R4 (this): grid = (chunk, batch), x-fastest dispatch. Each block writes
//       one contiguous 4 KB chunk of ONE image; the resident-block window
//       walks a single image sequentially — machine-level write stream is
//       shaped exactly like fillBuffer/old-phase-2, which hit 6.5 TB/s.
//
// The interpolation is recomputed for every batch (16x). Compute is free
// (VALUBusy 0.62% in R2) and the inputs (p2f 4 MB + bary 12 MB + faces +
// verts ~ 17 MB) are LLC-resident after the first image pass, so the
// redundant reads never touch HBM.
__global__ __launch_bounds__(BLOCK) void uv_fused(
    const float* __restrict__ verts,   // (16, 6890, 3) f32 — only batch 0 read
    const int*   __restrict__ faces,   // (13776, 3) int32
    const int*   __restrict__ p2f,     // (H, W) int32
    const float* __restrict__ bary,    // (H, W, 3) f32
    float*       __restrict__ out)     // (16, H, W, 3) f32
{
    const int j = blockIdx.x * BLOCK + threadIdx.x;  // float4 idx within image
    const int n = blockIdx.y;                        // batch image

    const int F = 4 * j;          // first float index in the image
    const int p = F / 3;          // first pixel covered
    const int c = F - 3 * p;      // component offset within pixel p (0..2)
    // floats [F, F+4) = pixel p comps [c..2] then pixel p+1 comps [0..c]
    // max j = MAPF4-1 -> p+1 = NPIX-1, never OOB.

    // --- interpolate pixel p -> A[0..2], pixel p+1 -> B[0..2] ---
    float A[3] = {0.f, 0.f, 0.f};
    float B[3] = {0.f, 0.f, 0.f};

    const int f0 = p2f[p];
    const int f1 = p2f[p + 1];

    if (f0 >= 0) {
        const int v0 = faces[3 * f0 + 0];
        const int v1 = faces[3 * f0 + 1];
        const int v2 = faces[3 * f0 + 2];
        const float w0 = bary[3 * p + 0];
        const float w1 = bary[3 * p + 1];
        const float w2 = bary[3 * p + 2];
        const float* a0 = verts + 3 * v0;   // batch-0 slice (83 KB, L1-hot)
        const float* a1 = verts + 3 * v1;
        const float* a2 = verts + 3 * v2;
        #pragma unroll
        for (int d = 0; d < 3; ++d)
            A[d] = w0 * a0[d] + w1 * a1[d] + w2 * a2[d];
    }
    if (f1 >= 0) {
        const int v0 = faces[3 * f1 + 0];
        const int v1 = faces[3 * f1 + 1];
        const int v2 = faces[3 * f1 + 2];
        const float w0 = bary[3 * (p + 1) + 0];
        const float w1 = bary[3 * (p + 1) + 1];
        const float w2 = bary[3 * (p + 1) + 2];
        const float* a0 = verts + 3 * v0;
        const float* a1 = verts + 3 * v1;
        const float* a2 = verts + 3 * v2;
        #pragma unroll
        for (int d = 0; d < 3; ++d)
            B[d] = w0 * a0[d] + w1 * a1[d] + w2 * a2[d];
    }

    // assemble this thread's float4: r[k] = (c+k < 3) ? A[c+k] : B[c+k-3]
    vfloat4 r;
    #pragma unroll
    for (int k = 0; k < 4; ++k) {
        const int ck = c + k;
        r[k] = (ck < 3) ? A[ck] : B[ck - 3];
    }

    // Single dense NT store into this block's image. Per-channel write
    // stream is sequential within one image — fillBuffer-shaped.
    __builtin_nontemporal_store(r, (vfloat4*)out + (size_t)n * MAPF4 + j);
}

extern "C" void kernel_launch(void* const* d_in, const int* in_sizes, int n_in,
                              void* d_out, int out_size, void* d_ws, size_t ws_size,
                              hipStream_t stream) {
    const float* verts = (const float*)d_in[0];   // (16, 6890, 3) f32
    const int*   faces = (const int*)d_in[1];     // (13776, 3) int32
    const int*   p2f   = (const int*)d_in[2];     // (1024, 1024) int32
    const float* bary  = (const float*)d_in[3];   // (1024, 1024, 3) f32
    float*       out   = (float*)d_out;           // (16, 1024, 1024, 3) f32

    dim3 grid(CHUNKS, NB);                        // (3072, 16), x-fastest
    uv_fused<<<grid, dim3(BLOCK), 0, stream>>>(verts, faces, p2f, bary, out);
}

// Round 5
// 243.419 us; speedup vs baseline: 2.2459x; 2.2459x over previous
//
#include <hip/hip_runtime.h>

// Problem constants (from reference)
constexpr int NPIX  = 1024 * 1024;    // pixels
constexpr int NB    = 16;             // batch replication factor
constexpr int BLOCK = 256;
constexpr int MAPF4 = NPIX * 3 / 4;   // float4s per batch image = 786432

// Native vector type — __builtin_nontemporal_store rejects HIP_vector_type.
typedef float vfloat4 __attribute__((ext_vector_type(4)));

// Wire dtypes (prior session): verts/bary f32, faces/p2f int32, out f32.
// out(n,h,w,d) is batch-invariant (reference gathers all batches from
// batch-0 face attrs; batch-0 packing offset is 0).
//
// R5: fused one-compute/16-store, with BOTH R4 root causes removed:
//   bug 1 (rule #20): r[k]=(ck<3)?A[ck]:B[ck-3] runtime-indexed arrays ->
//     scratch (VGPR 20->12, WRITE_SIZE 513 MB = 201 out + ~300 scratch).
//     Fix: A0..A2/B0..B2 scalars + branchless cndmask permute below.
//   bug 2: 16x recompute multiplied divergent vert/face gathers 16x ->
//     L1/TA serialization (FETCH 67 MB, occupancy 86%, VALU 0.6%, 388 us).
//     Fix: back to compute-ONCE per float4 (R3 structure), gathers at 1x.
// Store shape kept from R3 (counter-verified dense): thread j owns output
// float4 j of every image; per wave-instruction = 64 lanes x contiguous
// 16 B = 1 KB full lines. Batch order rotated per wave to decorrelate the
// 12 MiB (3*2^22) inter-batch stride streams.
__global__ __launch_bounds__(BLOCK) void uv_fused(
    const float* __restrict__ verts,   // (16, 6890, 3) f32 — only batch 0 read
    const int*   __restrict__ faces,   // (13776, 3) int32
    const int*   __restrict__ p2f,     // (H, W) int32
    const float* __restrict__ bary,    // (H, W, 3) f32
    float*       __restrict__ out)     // (16, H, W, 3) f32
{
    const int j = blockIdx.x * BLOCK + threadIdx.x;  // global float4 idx
    // grid * BLOCK == MAPF4 exactly; no tail check needed.

    const int F = 4 * j;          // first float index in the image
    const int p = F / 3;          // first pixel covered (magic-mul)
    const int c = F - 3 * p;      // component offset within pixel p (0..2)
    // floats [F,F+4) = pixel p comps [c..2] then pixel p+1 comps [0..c].
    // max j = MAPF4-1 -> p+1 = NPIX-1, in bounds.

    const int f0 = p2f[p];
    const int f1 = p2f[p + 1];

    // --- interpolate pixel p -> A0..A2, pixel p+1 -> B0..B2 (SCALARS) ---
    float A0 = 0.f, A1 = 0.f, A2 = 0.f;
    float B0 = 0.f, B1 = 0.f, B2 = 0.f;

    if (f0 >= 0) {
        const int v0 = faces[3 * f0 + 0];
        const int v1 = faces[3 * f0 + 1];
        const int v2 = faces[3 * f0 + 2];
        const float w0 = bary[3 * p + 0];
        const float w1 = bary[3 * p + 1];
        const float w2 = bary[3 * p + 2];
        const float* a0 = verts + 3 * v0;   // batch-0 slice (83 KB, cache-hot)
        const float* a1 = verts + 3 * v1;
        const float* a2 = verts + 3 * v2;
        A0 = w0 * a0[0] + w1 * a1[0] + w2 * a2[0];
        A1 = w0 * a0[1] + w1 * a1[1] + w2 * a2[1];
        A2 = w0 * a0[2] + w1 * a1[2] + w2 * a2[2];
    }
    if (f1 >= 0) {
        const int v0 = faces[3 * f1 + 0];
        const int v1 = faces[3 * f1 + 1];
        const int v2 = faces[3 * f1 + 2];
        const float w0 = bary[3 * (p + 1) + 0];
        const float w1 = bary[3 * (p + 1) + 1];
        const float w2 = bary[3 * (p + 1) + 2];
        const float* a0 = verts + 3 * v0;
        const float* a1 = verts + 3 * v1;
        const float* a2 = verts + 3 * v2;
        B0 = w0 * a0[0] + w1 * a1[0] + w2 * a2[0];
        B1 = w0 * a0[1] + w1 * a1[1] + w2 * a2[1];
        B2 = w0 * a0[2] + w1 * a1[2] + w2 * a2[2];
    }

    // Branchless component permute — pure v_cndmask on scalars, no arrays,
    // no scratch (R4's rule-#20 fix).
    //   c=0: A0 A1 A2 B0 | c=1: A1 A2 B0 B1 | c=2: A2 B0 B1 B2
    const bool c0 = (c == 0);
    const bool c1 = (c == 1);
    vfloat4 r;
    r[0] = c0 ? A0 : (c1 ? A1 : A2);
    r[1] = c0 ? A1 : (c1 ? A2 : B0);
    r[2] = c0 ? A2 : (c1 ? B0 : B1);
    r[3] = c0 ? B0 : (c1 ? B1 : B2);

    // 16 dense NT stores, batch order rotated per wave to break the
    // 12 MiB power-of-two stride correlation across streams.
    const int rot = (blockIdx.x * 4 + (threadIdx.x >> 6)) & (NB - 1);
    vfloat4* const base = (vfloat4*)out + j;
    #pragma unroll
    for (int n = 0; n < NB; ++n) {
        const int bidx = (n + rot) & (NB - 1);
        __builtin_nontemporal_store(r, base + (size_t)bidx * MAPF4);
    }
}

extern "C" void kernel_launch(void* const* d_in, const int* in_sizes, int n_in,
                              void* d_out, int out_size, void* d_ws, size_t ws_size,
                              hipStream_t stream) {
    const float* verts = (const float*)d_in[0];   // (16, 6890, 3) f32
    const int*   faces = (const int*)d_in[1];     // (13776, 3) int32
    const int*   p2f   = (const int*)d_in[2];     // (1024, 1024) int32
    const float* bary  = (const float*)d_in[3];   // (1024, 1024, 3) f32
    float*       out   = (float*)d_out;           // (16, 1024, 1024, 3) f32

    const int grid = MAPF4 / BLOCK;               // 3072 blocks, exact
    uv_fused<<<grid, BLOCK, 0, stream>>>(verts, faces, p2f, bary, out);
}

// Round 6
// 237.560 us; speedup vs baseline: 2.3013x; 1.0247x over previous
//
#include <hip/hip_runtime.h>

// Problem constants (from reference)
constexpr int NPIX  = 1024 * 1024;    // pixels
constexpr int NB    = 16;             // batch replication factor
constexpr int BLOCK = 256;
constexpr int MAPF4 = NPIX * 3 / 4;   // float4s per batch image = 786432

typedef float vfloat4 __attribute__((ext_vector_type(4)));

// Wire dtypes (prior session): verts/bary f32, faces/p2f int32, out f32.
// out(n,h,w,d) is batch-invariant (reference gathers all batches from
// batch-0 face attrs; batch-0 packing offset is 0).
//
// R6 = R5 with ONE change: cached stores instead of nontemporal.
//   Counter-verified history:
//   R2: NT + 48B-lane-stride -> partial lines reached HBM UNMERGED
//       (WRITE_SIZE 1.82x) -> proves NT bypasses L2 write-combining.
//   R5: NT + dense lines, 16 streams/wave at 12 MiB stride -> clean
//       WRITE_SIZE but ~73 us (~2x write floor): NT injects 16-way
//       interleaved bursts straight to DRAM -> row thrash beyond the
//       controller's reorder window.
//   R6 theory: cached stores let the 32 MB L2 accumulate dirty lines and
//       evict them in large address-sorted batches -> fillBuffer-like row
//       locality at DRAM despite interleaved issue. Output is never
//       re-read, so L2 pollution costs nothing but mild input eviction.
__global__ __launch_bounds__(BLOCK) void uv_fused(
    const float* __restrict__ verts,   // (16, 6890, 3) f32 — only batch 0 read
    const int*   __restrict__ faces,   // (13776, 3) int32
    const int*   __restrict__ p2f,     // (H, W) int32
    const float* __restrict__ bary,    // (H, W, 3) f32
    float*       __restrict__ out)     // (16, H, W, 3) f32
{
    const int j = blockIdx.x * BLOCK + threadIdx.x;  // global float4 idx
    // grid * BLOCK == MAPF4 exactly; no tail check needed.

    const int F = 4 * j;          // first float index in the image
    const int p = F / 3;          // first pixel covered (magic-mul)
    const int c = F - 3 * p;      // component offset within pixel p (0..2)
    // floats [F,F+4) = pixel p comps [c..2] then pixel p+1 comps [0..c].
    // max j = MAPF4-1 -> p+1 = NPIX-1, in bounds.

    const int f0 = p2f[p];
    const int f1 = p2f[p + 1];

    // --- interpolate pixel p -> A0..A2, pixel p+1 -> B0..B2 (SCALARS,
    // rule #20: no runtime-indexed arrays -> no scratch) ---
    float A0 = 0.f, A1 = 0.f, A2 = 0.f;
    float B0 = 0.f, B1 = 0.f, B2 = 0.f;

    if (f0 >= 0) {
        const int v0 = faces[3 * f0 + 0];
        const int v1 = faces[3 * f0 + 1];
        const int v2 = faces[3 * f0 + 2];
        const float w0 = bary[3 * p + 0];
        const float w1 = bary[3 * p + 1];
        const float w2 = bary[3 * p + 2];
        const float* a0 = verts + 3 * v0;   // batch-0 slice (83 KB, cache-hot)
        const float* a1 = verts + 3 * v1;
        const float* a2 = verts + 3 * v2;
        A0 = w0 * a0[0] + w1 * a1[0] + w2 * a2[0];
        A1 = w0 * a0[1] + w1 * a1[1] + w2 * a2[1];
        A2 = w0 * a0[2] + w1 * a1[2] + w2 * a2[2];
    }
    if (f1 >= 0) {
        const int v0 = faces[3 * f1 + 0];
        const int v1 = faces[3 * f1 + 1];
        const int v2 = faces[3 * f1 + 2];
        const float w0 = bary[3 * (p + 1) + 0];
        const float w1 = bary[3 * (p + 1) + 1];
        const float w2 = bary[3 * (p + 1) + 2];
        const float* a0 = verts + 3 * v0;
        const float* a1 = verts + 3 * v1;
        const float* a2 = verts + 3 * v2;
        B0 = w0 * a0[0] + w1 * a1[0] + w2 * a2[0];
        B1 = w0 * a0[1] + w1 * a1[1] + w2 * a2[1];
        B2 = w0 * a0[2] + w1 * a1[2] + w2 * a2[2];
    }

    // Branchless component permute — pure v_cndmask on scalars.
    //   c=0: A0 A1 A2 B0 | c=1: A1 A2 B0 B1 | c=2: A2 B0 B1 B2
    const bool c0 = (c == 0);
    const bool c1 = (c == 1);
    vfloat4 r;
    r[0] = c0 ? A0 : (c1 ? A1 : A2);
    r[1] = c0 ? A1 : (c1 ? A2 : B0);
    r[2] = c0 ? A2 : (c1 ? B0 : B1);
    r[3] = c0 ? B0 : (c1 ? B1 : B2);

    // 16 dense CACHED stores (L2 write-combining + sorted eviction),
    // batch order rotated per wave to decorrelate the 12 MiB-stride streams.
    const int rot = (blockIdx.x * 4 + (threadIdx.x >> 6)) & (NB - 1);
    vfloat4* const base = (vfloat4*)out + j;
    #pragma unroll
    for (int n = 0; n < NB; ++n) {
        const int bidx = (n + rot) & (NB - 1);
        base[(size_t)bidx * MAPF4] = r;
    }
}

extern "C" void kernel_launch(void* const* d_in, const int* in_sizes, int n_in,
                              void* d_out, int out_size, void* d_ws, size_t ws_size,
                              hipStream_t stream) {
    const float* verts = (const float*)d_in[0];   // (16, 6890, 3) f32
    const int*   faces = (const int*)d_in[1];     // (13776, 3) int32
    const int*   p2f   = (const int*)d_in[2];     // (1024, 1024) int32
    const float* bary  = (const float*)d_in[3];   // (1024, 1024, 3) f32
    float*       out   = (float*)d_out;           // (16, 1024, 1024, 3) f32

    const int grid = MAPF4 / BLOCK;               // 3072 blocks, exact
    uv_fused<<<grid, BLOCK, 0, stream>>>(verts, faces, p2f, bary, out);
}